// Round 12
// baseline (744.327 us; speedup 1.0000x reference)
//
#include <hip/hip_runtime.h>

#define NN 100000
#define NE 1600000
#define HID 128
#define ODIM 64
#define NBK 196          // ceil(NN/512) buckets of 512 nodes
#define BSHIFT 9
#define BGRID 512        // k_bin main blocks
#define CVTB 48          // extra k_bin blocks doing weight cvt
#define CHUNK 3125       // NE / BGRID (exact)
#define BITER 13         // ceil(CHUNK/256)
#define BINCAP 12288     // records per bucket region (mean ~9940 incl pad)
#define SMAX 4504        // LDS staging records >= 3125 + 196*7 = 4497
#define LMAX 568         // line map entries >= SMAX/8

typedef unsigned int u32;
typedef unsigned short u16;
typedef __bf16 bf16x8 __attribute__((ext_vector_type(8)));
typedef float f32x4 __attribute__((ext_vector_type(4)));

__device__ __forceinline__ float bf_lo(u32 p){ return __uint_as_float(p << 16); }
__device__ __forceinline__ float bf_hi(u32 p){ return __uint_as_float(p & 0xffff0000u); }
__device__ __forceinline__ u16 f2bf(float f){
  u32 u = __float_as_uint(f);
  u += 0x7fffu + ((u >> 16) & 1u);   // RTNE
  return (u16)(u >> 16);
}
__device__ __forceinline__ bf16x8 ld8bf(const u16* p){ return *(const bf16x8*)p; }
__device__ __forceinline__ bf16x8 cvt8(const float* p){
  union { bf16x8 v; u16 s[8]; } r;
#pragma unroll
  for (int i = 0; i < 8; i++) r.s[i] = f2bf(p[i]);
  return r.v;
}

// g/h1/h2 use SLICED layout: tensor[slice 0..7][node][16 dims] bf16.
// Slice s of node n starts at 16-bf16 offset (s*NN + n)*16.

// -- fused edge pass + bin, LDS-staged full-line output; extra blocks cvt
//    weights. minmax: mm[0]=max(~bits(min)), mm[1]=max(bits(max)), 0-init.
__global__ __launch_bounds__(256) void k_bin(
    const float* __restrict__ eattr, const int* __restrict__ erow,
    const int* __restrict__ ecol, u32* __restrict__ bcur,
    uint2* __restrict__ bin, u32* __restrict__ minmax,
    const float* __restrict__ W1, const float* __restrict__ W2,
    const float* __restrict__ Wr, u16* __restrict__ W1b,
    u16* __restrict__ W2b, u16* __restrict__ Wrb){
  int tid = threadIdx.x;
  if (blockIdx.x >= BGRID){                    // weight-conversion blocks
    int i = (blockIdx.x - BGRID) * 256 + tid;  // 12288 float4 slots
    const float* src; u16* dst; int off;
    if (i < 4096){ src = W1; dst = W1b; off = i; }
    else if (i < 8192){ src = W2; dst = W2b; off = i - 4096; }
    else { src = Wr; dst = Wrb; off = i - 8192; }
    float4 v = ((const float4*)src)[off];
    uint2 o;
    o.x = (u32)f2bf(v.x) | ((u32)f2bf(v.y) << 16);
    o.y = (u32)f2bf(v.z) | ((u32)f2bf(v.w) << 16);
    ((uint2*)dst)[off] = o;
    return;
  }
  __shared__ u32 lcnt[NBK], lofs[NBK], gb[NBK];
  __shared__ u32 scn[256];
  __shared__ u16 lmap[LMAX];
  __shared__ uint2 stage[SMAX];
  __shared__ u32 Tt;
  __shared__ float smin[4], smax[4];
  for (int t = tid; t < NBK; t += 256) lcnt[t] = 0;
  __syncthreads();
  int base = blockIdx.x * CHUNK;
  float lmin = __uint_as_float(0x7f800000u), lmax = 0.f;
  u32 pk[BITER]; float mv[BITER]; u32 sv[BITER];
#pragma unroll
  for (int it = 0; it < BITER; it++){
    int idx = it * 256 + tid;
    u32 p = 0xFFFFFFFFu; float m = 0.f; u32 s = 0;
    if (idx < CHUNK){
      int e = base + idx;
      float4 a = ((const float4*)eattr)[e];
      m = 0.25f * (a.x + a.y + a.z + a.w);
      lmin = fminf(lmin, m); lmax = fmaxf(lmax, m);
      int c = ecol[e];
      s = (u32)erow[e]; if (s >= NN) s = 0;    // never triggers (randint<NN)
      if ((u32)c < NN){
        u32 b = (u32)c >> BSHIFT;
        u32 r = atomicAdd(&lcnt[b], 1u);       // r < CHUNK < 4096
        p = (b << 21) | (((u32)c & 511u) << 12) | r;
      }
    }
    pk[it] = p; mv[it] = m; sv[it] = s;
  }
  __syncthreads();
  // padded scan over buckets; global region alloc; line->bucket map
  u32 na = 0, n = 0;
  if (tid < NBK){ n = lcnt[tid]; na = (n + 7u) & ~7u; }
  scn[tid] = na; __syncthreads();
  for (int s = 1; s < 256; s <<= 1){
    u32 t = (tid >= s) ? scn[tid - s] : 0;
    __syncthreads();
    scn[tid] += t;
    __syncthreads();
  }
  u32 ex = scn[tid] - na;
  if (tid < NBK){
    lofs[tid] = ex;
    u32 g = 0x80000000u;
    if (na){
      u32 gl = atomicAdd(&bcur[tid], na);      // bcur 0-init by memset
      if (gl + na <= BINCAP) g = (u32)tid * BINCAP + gl;
    }
    gb[tid] = g;
    for (u32 l = ex >> 3; l < (ex + na) >> 3; l++) lmap[l] = (u16)tid;
    uint2 sent; sent.x = 0xFFFFFFFFu; sent.y = 0u;
    for (u32 k = n; k < na; k++) stage[ex + k] = sent;   // pad slots only
  }
  if (tid == 255) Tt = scn[255];
  __syncthreads();
  // place records bucket-major in LDS
#pragma unroll
  for (int it = 0; it < BITER; it++){
    u32 p = pk[it];
    if (p == 0xFFFFFFFFu) continue;
    uint2 rec; rec.x = sv[it] | (((p >> 12) & 511u) << 17); rec.y = __float_as_uint(mv[it]);
    stage[lofs[p >> 21] + (p & 4095u)] = rec;
  }
  __syncthreads();
  // stream out: consecutive threads -> consecutive slots in full-line runs
  u32 T = Tt;
  for (u32 i = tid; i < T; i += 256){
    u32 b = lmap[i >> 3];
    u32 g = gb[b];
    if (g != 0x80000000u) bin[g + (i - lofs[b])] = stage[i];
  }
  // min/max reduce + global update (0-init compatible encoding)
  for (int off = 32; off; off >>= 1){
    lmin = fminf(lmin, __shfl_xor(lmin, off));
    lmax = fmaxf(lmax, __shfl_xor(lmax, off));
  }
  int wid = tid >> 6, lane = tid & 63;
  if (lane == 0){ smin[wid] = lmin; smax[wid] = lmax; }
  __syncthreads();
  if (tid == 0){
    float mn = fminf(fminf(smin[0], smin[1]), fminf(smin[2], smin[3]));
    float mx = fmaxf(fmaxf(smax[0], smax[1]), fmaxf(smax[2], smax[3]));
    atomicMax(&minmax[0], ~__float_as_uint(mn));  // nonneg: bit order == value order
    atomicMax(&minmax[1], __float_as_uint(mx));
  }
}

// -- per-bucket sort: strip sentinels, w from m, build 4B-packed csr ------
__global__ __launch_bounds__(1024) void k_sort(
    const u32* __restrict__ bcur, const uint2* __restrict__ bin,
    const u32* __restrict__ minmax, u32* __restrict__ csr,
    int* __restrict__ row_start, int* __restrict__ counts, float* __restrict__ dis){
  int b = blockIdx.x;
  int bb = b * BINCAP, be = bb + (int)bcur[b];
  float mn  = __uint_as_float(~minmax[0]);
  float mx  = __uint_as_float(minmax[1]);
  float rng = mx - mn;
  bool flat = !(rng > 1e-8f);
  float inv = 1.f / (rng + 1e-8f);
  __shared__ u32 cnt[512], off[512], cur[512], degfx[512];
  int tid = threadIdx.x;
  if (tid < 512){ cnt[tid] = 0; degfx[tid] = 0; }
  __syncthreads();
  for (int i = bb + tid; i < be; i += 1024){
    uint2 r = bin[i];
    if (r.x == 0xFFFFFFFFu) continue;          // sentinel
    u32 d = (r.x >> 17) & 511u;
    float w = flat ? 1.f : fmaxf(1.f - (__uint_as_float(r.y) - mn) * inv, 0.f);
    atomicAdd(&cnt[d], 1u);
    atomicAdd(&degfx[d], (u32)(w * 1048576.f + 0.5f));   // 2^20 fixed point
  }
  __syncthreads();
  u32 v = 0;
  if (tid < 512){ v = cnt[tid]; off[tid] = v; }
  __syncthreads();
  for (int s = 1; s < 512; s <<= 1){
    u32 t = 0;
    if (tid < 512 && tid >= s) t = off[tid - s];
    __syncthreads();
    if (tid < 512) off[tid] += t;
    __syncthreads();
  }
  if (tid < 512){
    u32 ex = off[tid] - v;                     // exclusive scan
    cur[tid] = ex;
    int node = (b << BSHIFT) + tid;
    if (node < NN){
      row_start[node] = bb + (int)ex;          // csr is bucket-padded; absolute index
      counts[node] = (int)v;
      dis[node] = rsqrtf(1.f + (float)degfx[tid] * (1.f / 1048576.f));
    }
  }
  __syncthreads();
  for (int i = bb + tid; i < be; i += 1024){
    uint2 r = bin[i];
    if (r.x == 0xFFFFFFFFu) continue;
    u32 d = (r.x >> 17) & 511u;
    float w = flat ? 1.f : fmaxf(1.f - (__uint_as_float(r.y) - mn) * inv, 0.f);
    u32 wq = (u32)(w * 32767.f + 0.5f);        // 15-bit fixed point
    u32 pos = (u32)bb + atomicAdd(&cur[d], 1u);
    csr[pos] = (r.x & 0x1FFFFu) | (wq << 17);  // src:17 | w:15, 4B record
  }
}

// -- bf16 MFMA GEMM: G = dis[m]*(A @ Bt^T), G in SLICED layout ------------
// One block = 32 rows x all 128 cols. A: f32 row-major (layer1) or sliced bf16.
template <bool A_F32>
__global__ __launch_bounds__(256) void k_gemm128(
    const void* __restrict__ Av, const u16* __restrict__ Bt,
    const float* __restrict__ dis, u16* __restrict__ G){
  int wave = threadIdx.x >> 6, lane = threadIdx.x & 63;
  int m0 = blockIdx.x * 32;
  int m = lane & 15, q = lane >> 4;
  const float* a0f = (const float*)Av + (size_t)(m0 + m) * HID;
  const float* a1f = a0f + (size_t)16 * HID;
  const u16* Ab = (const u16*)Av;
  const u16* brow0 = Bt + (size_t)(wave * 16 + m) * HID;
  const u16* brow1 = brow0 + (size_t)64 * HID;
  f32x4 acc00 = {0.f,0.f,0.f,0.f}, acc01 = {0.f,0.f,0.f,0.f};
  f32x4 acc10 = {0.f,0.f,0.f,0.f}, acc11 = {0.f,0.f,0.f,0.f};
#pragma unroll
  for (int kb = 0; kb < HID; kb += 32){
    int k = kb + q * 8;
    bf16x8 af0, af1;
    if (A_F32){
      af0 = cvt8(a0f + k); af1 = cvt8(a1f + k);
    } else {
      const u16* p = Ab + (size_t)(k >> 4) * (NN * 16) + (size_t)(m0 + m) * 16 + (k & 15);
      af0 = ld8bf(p); af1 = ld8bf(p + 256);    // +16 rows
    }
    bf16x8 bf0 = ld8bf(brow0 + k);
    bf16x8 bf1 = ld8bf(brow1 + k);
    acc00 = __builtin_amdgcn_mfma_f32_16x16x32_bf16(af0, bf0, acc00, 0, 0, 0);
    acc01 = __builtin_amdgcn_mfma_f32_16x16x32_bf16(af0, bf1, acc01, 0, 0, 0);
    acc10 = __builtin_amdgcn_mfma_f32_16x16x32_bf16(af1, bf0, acc10, 0, 0, 0);
    acc11 = __builtin_amdgcn_mfma_f32_16x16x32_bf16(af1, bf1, acc11, 0, 0, 0);
  }
  // sliced store: col wave*16+m -> slice=wave; col+64 -> slice=wave+4
  u16* b0 = G + (size_t)wave * (NN * 16) + (size_t)(m0 + q * 4) * 16 + m;
  u16* b1 = G + (size_t)(wave + 4) * (NN * 16) + (size_t)(m0 + q * 4) * 16 + m;
#pragma unroll
  for (int r = 0; r < 4; r++){
    float d0 = dis[m0 + q * 4 + r];
    float d1 = dis[m0 + 16 + q * 4 + r];
    b0[r * 16]       = f2bf(acc00[r] * d0);
    b1[r * 16]       = f2bf(acc01[r] * d0);
    b0[256 + r * 16] = f2bf(acc10[r] * d1);
    b1[256 + r * 16] = f2bf(acc11[r] * d1);
  }
}

// ------- aggregation, XCD-sliced: block handles slice (blockIdx&7) for 16
// nodes; wave = 4 nodes; 8 edges x 8 lanes per gather; shfl-xor reduction.
// h_i = relu( dis_i * (sum_e w_e * g[src_e] + g_i) + b )
__global__ __launch_bounds__(256) void k_aggregate(
    const int* __restrict__ row_start, const int* __restrict__ counts,
    const u32* __restrict__ csr, const float* __restrict__ dis,
    const u16* __restrict__ g, const float* __restrict__ bias,
    u16* __restrict__ hout){
  int s = blockIdx.x & 7;                       // slice -> XCD (round-robin)
  int node0 = (blockIdx.x >> 3) * 16 + (threadIdx.x >> 6) * 4;
  int lane = threadIdx.x & 63;
  int sub = lane & 7, egrp = lane >> 3;
  const u32* gs = (const u32*)g + (size_t)s * (NN * 8);   // 3.2MB slice, L2-resident
  u32* hs = (u32*)hout + (size_t)s * (NN * 8);
  float2 bv = ((const float2*)bias)[s * 8 + sub];
#pragma unroll
  for (int nn = 0; nn < 4; nn++){
    int node = node0 + nn;
    int srow = row_start[node], c = counts[node];
    float a0 = 0.f, a1 = 0.f;
    for (int base = 0; base < c; base += 64){
      int nch = min(64, c - base);
      int pwAll = 0;
      if (lane < nch) pwAll = (int)__builtin_nontemporal_load(&csr[srow + base + lane]);
      int j = 0;
      for (; j + 16 <= nch; j += 16){
        u32 pw0 = (u32)__shfl(pwAll, j + egrp);
        u32 pw1 = (u32)__shfl(pwAll, j + 8 + egrp);
        u32 pv0 = gs[(pw0 & 0x1FFFFu) * 8u + sub];
        u32 pv1 = gs[(pw1 & 0x1FFFFu) * 8u + sub];
        float w0 = (float)(pw0 >> 17) * (1.f / 32767.f);
        float w1 = (float)(pw1 >> 17) * (1.f / 32767.f);
        a0 += w0 * bf_lo(pv0); a1 += w0 * bf_hi(pv0);
        a0 += w1 * bf_lo(pv1); a1 += w1 * bf_hi(pv1);
      }
      for (; j < nch; j += 8){
        u32 pw = (u32)__shfl(pwAll, j + egrp);  // lanes >= nch hold 0 -> w=0
        u32 pv = gs[(pw & 0x1FFFFu) * 8u + sub];
        float w = (float)(pw >> 17) * (1.f / 32767.f);
        a0 += w * bf_lo(pv); a1 += w * bf_hi(pv);
      }
    }
    a0 += __shfl_xor(a0, 8);  a1 += __shfl_xor(a1, 8);
    a0 += __shfl_xor(a0, 16); a1 += __shfl_xor(a1, 16);
    a0 += __shfl_xor(a0, 32); a1 += __shfl_xor(a1, 32);
    u32 sv = gs[(u32)node * 8u + sub];          // self-loop term g_i
    float di = dis[node];
    float o0 = fmaxf((a0 + bf_lo(sv)) * di + bv.x, 0.f);
    float o1 = fmaxf((a1 + bf_hi(sv)) * di + bv.y, 0.f);
    if (egrp == 0)
      hs[(u32)node * 8u + sub] = (u32)f2bf(o0) | ((u32)f2bf(o1) << 16);
  }
}

// -- readout: out[M,64] = [h1|h2] @ Wr^T + br (f32 out); h sliced ---------
__global__ __launch_bounds__(256) void k_readout(
    const u16* __restrict__ h1, const u16* __restrict__ h2,
    const u16* __restrict__ Wrb, const float* __restrict__ br, float* __restrict__ out){
  int wave = threadIdx.x >> 6, lane = threadIdx.x & 63;
  int m0 = blockIdx.x * 32;
  int n0 = wave * 16;
  int m = lane & 15, q = lane >> 4;
  const u16* b = Wrb + (size_t)(n0 + m) * (2 * HID);
  f32x4 acc0 = {0.f,0.f,0.f,0.f}, acc1 = {0.f,0.f,0.f,0.f};
#pragma unroll
  for (int kb = 0; kb < HID; kb += 32){
    int k = kb + q * 8;
    const u16* p = h1 + (size_t)(k >> 4) * (NN * 16) + (size_t)(m0 + m) * 16 + (k & 15);
    bf16x8 bf = ld8bf(b + k);
    acc0 = __builtin_amdgcn_mfma_f32_16x16x32_bf16(ld8bf(p), bf, acc0, 0, 0, 0);
    acc1 = __builtin_amdgcn_mfma_f32_16x16x32_bf16(ld8bf(p + 256), bf, acc1, 0, 0, 0);
  }
#pragma unroll
  for (int kb = 0; kb < HID; kb += 32){
    int k = kb + q * 8;
    const u16* p = h2 + (size_t)(k >> 4) * (NN * 16) + (size_t)(m0 + m) * 16 + (k & 15);
    bf16x8 bf = ld8bf(b + HID + k);
    acc0 = __builtin_amdgcn_mfma_f32_16x16x32_bf16(ld8bf(p), bf, acc0, 0, 0, 0);
    acc1 = __builtin_amdgcn_mfma_f32_16x16x32_bf16(ld8bf(p + 256), bf, acc1, 0, 0, 0);
  }
  float bias = br[n0 + m];
  float* crow0 = out + (size_t)(m0 + q * 4) * ODIM + n0 + m;
  float* crow1 = crow0 + (size_t)16 * ODIM;
#pragma unroll
  for (int r = 0; r < 4; r++){
    crow0[(size_t)r * ODIM] = acc0[r] + bias;
    crow1[(size_t)r * ODIM] = acc1[r] + bias;
  }
}

// ---------------- launch --------------------------------------------------
extern "C" void kernel_launch(void* const* d_in, const int* in_sizes, int n_in,
                              void* d_out, int out_size, void* d_ws, size_t ws_size,
                              hipStream_t stream){
  const float* x     = (const float*)d_in[0];
  const int*   eidx  = (const int*)d_in[1];
  const float* eattr = (const float*)d_in[2];
  const float* W1    = (const float*)d_in[3];
  const float* b1    = (const float*)d_in[4];
  const float* W2    = (const float*)d_in[5];
  const float* b2    = (const float*)d_in[6];
  const float* Wr    = (const float*)d_in[7];
  const float* br    = (const float*)d_in[8];
  const int* erow  = eidx;        // edge_index[0]
  const int* ecol  = eidx + NE;   // edge_index[1]

  char* w = (char*)d_ws;
  auto carve = [&](size_t bytes) -> void* {
    void* p = (void*)w;
    w += (bytes + 255) & ~(size_t)255;
    return p;
  };
  u32* csr       = (u32*)carve((size_t)NBK * BINCAP * 4);    // bucket-padded, 4B recs
  u32* bcur      = (u32*)carve(256 * 4);      // contiguous with minmax (one memset)
  u32* minmax    = (u32*)carve(256);
  int* row_start = (int*)carve((size_t)NN * 4);
  int* counts    = (int*)carve((size_t)NN * 4);
  float* dis     = (float*)carve((size_t)NN * 4);
  u16* W1b       = (u16*)carve((size_t)HID * HID * 2);
  u16* W2b       = (u16*)carve((size_t)HID * HID * 2);
  u16* Wrb       = (u16*)carve((size_t)ODIM * 2 * HID * 2);
  u16* g         = (u16*)carve((size_t)NN * HID * 2);
  u16* h1        = (u16*)carve((size_t)NN * HID * 2);
  u16* h2        = (u16*)carve((size_t)NN * HID * 2);
  uint2* bin     = (uint2*)h2;   // alias: bin dead after k_sort, h2 written in layer 2

  hipMemsetAsync(bcur, 0, 1024 + 256, stream);   // bcur + minmax (graph-capturable)
  k_bin<<<BGRID + CVTB, 256, 0, stream>>>(eattr, erow, ecol, bcur, bin, minmax,
                                          W1, W2, Wr, W1b, W2b, Wrb);
  k_sort<<<NBK, 1024, 0, stream>>>(bcur, bin, minmax, csr, row_start, counts, dis);

  // layer 1: g = dis * (x @ W1^T)  (f32 A converted inline; g sliced)
  k_gemm128<true><<<NN / 32, 256, 0, stream>>>(x, W1b, dis, g);
  k_aggregate<<<(NN / 16) * 8, 256, 0, stream>>>(row_start, counts, csr, dis, g, b1, h1);
  // layer 2
  k_gemm128<false><<<NN / 32, 256, 0, stream>>>(h1, W2b, dis, g);
  k_aggregate<<<(NN / 16) * 8, 256, 0, stream>>>(row_start, counts, csr, dis, g, b2, h2);
  // readout
  k_readout<<<NN / 32, 256, 0, stream>>>(h1, h2, Wrb, br, (float*)d_out);
}

// Round 13
// 385.636 us; speedup vs baseline: 1.9301x; 1.9301x over previous
//
#include <hip/hip_runtime.h>

#define NN 100000
#define NE 1600000
#define HID 128
#define ODIM 64
#define NBK 196          // ceil(NN/512) buckets of 512 nodes
#define BSHIFT 9
#define BGRID 512        // k_bin main blocks
#define CVTB 48          // extra k_bin blocks doing weight cvt
#define CHUNK 3125       // NE / BGRID (exact)
#define BITER 13         // ceil(CHUNK/256)
#define BINCAP 12288     // records per bucket region (mean ~9940 incl pad)
#define SMAX 4504        // LDS staging records >= 3125 + 196*7 = 4497
#define LMAX 568         // line map entries >= SMAX/8

typedef unsigned int u32;
typedef unsigned short u16;
typedef __bf16 bf16x8 __attribute__((ext_vector_type(8)));
typedef float f32x4 __attribute__((ext_vector_type(4)));
typedef float f32x2 __attribute__((ext_vector_type(2)));

__device__ __forceinline__ float bf_lo(u32 p){ return __uint_as_float(p << 16); }
__device__ __forceinline__ float bf_hi(u32 p){ return __uint_as_float(p & 0xffff0000u); }
__device__ __forceinline__ u16 f2bf(float f){
  u32 u = __float_as_uint(f);
  u += 0x7fffu + ((u >> 16) & 1u);   // RTNE
  return (u16)(u >> 16);
}
__device__ __forceinline__ bf16x8 ld8bf(const u16* p){ return *(const bf16x8*)p; }
__device__ __forceinline__ bf16x8 cvt8(const float* p){
  union { bf16x8 v; u16 s[8]; } r;
#pragma unroll
  for (int i = 0; i < 8; i++) r.s[i] = f2bf(p[i]);
  return r.v;
}

// -- fused edge pass + bin, LDS-staged full-line output; extra blocks cvt
//    weights. Per-wave privatized bucket counters (4x less LDS-atomic
//    contention). minmax: mm[0]=max(~bits(min)), mm[1]=max(bits(max)), 0-init.
__global__ __launch_bounds__(256) void k_bin(
    const float* __restrict__ eattr, const int* __restrict__ erow,
    const int* __restrict__ ecol, u32* __restrict__ bcur,
    uint2* __restrict__ bin, u32* __restrict__ minmax,
    const float* __restrict__ W1, const float* __restrict__ W2,
    const float* __restrict__ Wr, u16* __restrict__ W1b,
    u16* __restrict__ W2b, u16* __restrict__ Wrb){
  int tid = threadIdx.x;
  if (blockIdx.x >= BGRID){                    // weight-conversion blocks
    int i = (blockIdx.x - BGRID) * 256 + tid;  // 12288 float4 slots
    const float* src; u16* dst; int off;
    if (i < 4096){ src = W1; dst = W1b; off = i; }
    else if (i < 8192){ src = W2; dst = W2b; off = i - 4096; }
    else { src = Wr; dst = Wrb; off = i - 8192; }
    float4 v = ((const float4*)src)[off];
    uint2 o;
    o.x = (u32)f2bf(v.x) | ((u32)f2bf(v.y) << 16);
    o.y = (u32)f2bf(v.z) | ((u32)f2bf(v.w) << 16);
    ((uint2*)dst)[off] = o;
    return;
  }
  __shared__ u32 lcnt4[4 * NBK], wof4[4 * NBK];
  __shared__ u32 lofs[NBK], gb[NBK];
  __shared__ u32 scn[256];
  __shared__ u16 lmap[LMAX];
  __shared__ uint2 stage[SMAX];
  __shared__ u32 Tt;
  __shared__ float smin[4], smax[4];
  for (int t = tid; t < 4 * NBK; t += 256) lcnt4[t] = 0;
  __syncthreads();
  int base = blockIdx.x * CHUNK;
  int wid = tid >> 6, lane = tid & 63;
  float lmin = __uint_as_float(0x7f800000u), lmax = 0.f;
  u32 pk[BITER]; float mv[BITER]; u32 sv[BITER];
#pragma unroll
  for (int it = 0; it < BITER; it++){
    int idx = it * 256 + tid;
    u32 p = 0xFFFFFFFFu; float m = 0.f; u32 s = 0;
    if (idx < CHUNK){
      int e = base + idx;
      float4 a = ((const float4*)eattr)[e];
      m = 0.25f * (a.x + a.y + a.z + a.w);
      lmin = fminf(lmin, m); lmax = fmaxf(lmax, m);
      int c = ecol[e];
      s = (u32)erow[e]; if (s >= NN) s = 0;    // never triggers (randint<NN)
      if ((u32)c < NN){
        u32 b = (u32)c >> BSHIFT;
        u32 r = atomicAdd(&lcnt4[wid * NBK + b], 1u);   // r <= 13*64 < 4096
        p = (b << 21) | (((u32)c & 511u) << 12) | r;
      }
    }
    pk[it] = p; mv[it] = m; sv[it] = s;
  }
  __syncthreads();
  // combine per-wave counts; padded scan; global region alloc; line map
  u32 na = 0, n = 0;
  if (tid < NBK){
    u32 n0 = lcnt4[tid], n1 = lcnt4[NBK + tid];
    u32 n2 = lcnt4[2 * NBK + tid], n3 = lcnt4[3 * NBK + tid];
    n = n0 + n1 + n2 + n3;
    na = (n + 7u) & ~7u;
    wof4[tid] = 0; wof4[NBK + tid] = n0;
    wof4[2 * NBK + tid] = n0 + n1; wof4[3 * NBK + tid] = n0 + n1 + n2;
  }
  scn[tid] = na; __syncthreads();
  for (int s = 1; s < 256; s <<= 1){
    u32 t = (tid >= s) ? scn[tid - s] : 0;
    __syncthreads();
    scn[tid] += t;
    __syncthreads();
  }
  u32 ex = scn[tid] - na;
  if (tid < NBK){
    lofs[tid] = ex;
    u32 g = 0x80000000u;
    if (na){
      u32 gl = atomicAdd(&bcur[tid], na);      // bcur 0-init by memset
      if (gl + na <= BINCAP) g = (u32)tid * BINCAP + gl;
    }
    gb[tid] = g;
    for (u32 l = ex >> 3; l < (ex + na) >> 3; l++) lmap[l] = (u16)tid;
    uint2 sent; sent.x = 0xFFFFFFFFu; sent.y = 0u;
    for (u32 k = n; k < na; k++) stage[ex + k] = sent;   // pad slots only
  }
  if (tid == 255) Tt = scn[255];
  __syncthreads();
  // place records bucket-major in LDS
#pragma unroll
  for (int it = 0; it < BITER; it++){
    u32 p = pk[it];
    if (p == 0xFFFFFFFFu) continue;
    u32 b = p >> 21;
    uint2 rec; rec.x = sv[it] | (((p >> 12) & 511u) << 17); rec.y = __float_as_uint(mv[it]);
    stage[lofs[b] + wof4[wid * NBK + b] + (p & 4095u)] = rec;
  }
  __syncthreads();
  // stream out: consecutive threads -> consecutive slots in full-line runs
  u32 T = Tt;
  for (u32 i = tid; i < T; i += 256){
    u32 b = lmap[i >> 3];
    u32 g = gb[b];
    if (g != 0x80000000u) bin[g + (i - lofs[b])] = stage[i];
  }
  // min/max reduce + global update (0-init compatible encoding)
  for (int off = 32; off; off >>= 1){
    lmin = fminf(lmin, __shfl_xor(lmin, off));
    lmax = fmaxf(lmax, __shfl_xor(lmax, off));
  }
  if (lane == 0){ smin[wid] = lmin; smax[wid] = lmax; }
  __syncthreads();
  if (tid == 0){
    float mn = fminf(fminf(smin[0], smin[1]), fminf(smin[2], smin[3]));
    float mx = fmaxf(fmaxf(smax[0], smax[1]), fmaxf(smax[2], smax[3]));
    atomicMax(&minmax[0], ~__float_as_uint(mn));  // nonneg: bit order == value order
    atomicMax(&minmax[1], __float_as_uint(mx));
  }
}

// -- per-bucket sort: LDS-stage the bucket (<=98KB), one global read ------
__global__ __launch_bounds__(1024) void k_sort(
    const u32* __restrict__ bcur, const uint2* __restrict__ bin,
    const u32* __restrict__ minmax, u32* __restrict__ csr,
    int* __restrict__ row_start, int* __restrict__ counts, float* __restrict__ dis){
  int b = blockIdx.x;
  int bb = b * BINCAP, nrec = (int)bcur[b];
  float mn  = __uint_as_float(~minmax[0]);
  float mx  = __uint_as_float(minmax[1]);
  float rng = mx - mn;
  bool flat = !(rng > 1e-8f);
  float inv = 1.f / (rng + 1e-8f);
  __shared__ u32 cnt[512], off[512], cur[512], degfx[512];
  __shared__ uint2 sbin[BINCAP];               // 98 KB: whole bucket region
  int tid = threadIdx.x;
  if (tid < 512){ cnt[tid] = 0; degfx[tid] = 0; }
  __syncthreads();
  for (int i = tid; i < nrec; i += 1024){
    uint2 r = bin[bb + i];
    uint2 srec; srec.x = 0xFFFFFFFFu; srec.y = 0u;
    if (r.x != 0xFFFFFFFFu){                   // not sentinel
      u32 d = (r.x >> 17) & 511u;
      float w = flat ? 1.f : fmaxf(1.f - (__uint_as_float(r.y) - mn) * inv, 0.f);
      atomicAdd(&cnt[d], 1u);
      atomicAdd(&degfx[d], (u32)(w * 1048576.f + 0.5f));  // 2^20 fixed point
      srec.x = (r.x & 0x1FFFFu) | ((u32)(w * 32767.f + 0.5f) << 17);  // final csr word
      srec.y = d;
    }
    sbin[i] = srec;
  }
  __syncthreads();
  u32 v = 0;
  if (tid < 512){ v = cnt[tid]; off[tid] = v; }
  __syncthreads();
  for (int s = 1; s < 512; s <<= 1){
    u32 t = 0;
    if (tid < 512 && tid >= s) t = off[tid - s];
    __syncthreads();
    if (tid < 512) off[tid] += t;
    __syncthreads();
  }
  if (tid < 512){
    u32 ex = off[tid] - v;                     // exclusive scan
    cur[tid] = ex;
    int node = (b << BSHIFT) + tid;
    if (node < NN){
      row_start[node] = bb + (int)ex;          // csr is bucket-padded; absolute index
      counts[node] = (int)v;
      dis[node] = rsqrtf(1.f + (float)degfx[tid] * (1.f / 1048576.f));
    }
  }
  __syncthreads();
  for (int i = tid; i < nrec; i += 1024){
    uint2 s = sbin[i];
    if (s.x == 0xFFFFFFFFu) continue;          // src=0x1FFFF impossible (>=NN)
    u32 pos = (u32)bb + atomicAdd(&cur[s.y], 1u);
    csr[pos] = s.x;                            // src:17 | w:15, 4B record
  }
}

// -- bf16 MFMA GEMM: G[M,128] = dis[m]*(A[M,128] @ Bt[128,128]^T) ---------
// One block = 32 rows x ALL 128 cols (wave: 2 m-tiles x 2 n-tiles).
template <bool A_F32>
__global__ __launch_bounds__(256) void k_gemm128(
    const void* __restrict__ Av, const u16* __restrict__ Bt,
    const float* __restrict__ dis, u16* __restrict__ G){
  int wave = threadIdx.x >> 6, lane = threadIdx.x & 63;
  int m0 = blockIdx.x * 32;
  int m = lane & 15, q = lane >> 4;
  const float* a0f = (const float*)Av + (size_t)(m0 + m) * HID;
  const float* a1f = a0f + (size_t)16 * HID;
  const u16*   a0b = (const u16*)Av   + (size_t)(m0 + m) * HID;
  const u16*   a1b = a0b + (size_t)16 * HID;
  const u16* brow0 = Bt + (size_t)(wave * 16 + m) * HID;
  const u16* brow1 = brow0 + (size_t)64 * HID;
  f32x4 acc00 = {0.f,0.f,0.f,0.f}, acc01 = {0.f,0.f,0.f,0.f};
  f32x4 acc10 = {0.f,0.f,0.f,0.f}, acc11 = {0.f,0.f,0.f,0.f};
#pragma unroll
  for (int kb = 0; kb < HID; kb += 32){
    bf16x8 af0 = A_F32 ? cvt8(a0f + kb + q * 8) : ld8bf(a0b + kb + q * 8);
    bf16x8 af1 = A_F32 ? cvt8(a1f + kb + q * 8) : ld8bf(a1b + kb + q * 8);
    bf16x8 bf0 = ld8bf(brow0 + kb + q * 8);
    bf16x8 bf1 = ld8bf(brow1 + kb + q * 8);
    acc00 = __builtin_amdgcn_mfma_f32_16x16x32_bf16(af0, bf0, acc00, 0, 0, 0);
    acc01 = __builtin_amdgcn_mfma_f32_16x16x32_bf16(af0, bf1, acc01, 0, 0, 0);
    acc10 = __builtin_amdgcn_mfma_f32_16x16x32_bf16(af1, bf0, acc10, 0, 0, 0);
    acc11 = __builtin_amdgcn_mfma_f32_16x16x32_bf16(af1, bf1, acc11, 0, 0, 0);
  }
  u16* crow0 = G + (size_t)(m0 + q * 4) * HID + wave * 16 + m;
  u16* crow1 = crow0 + (size_t)16 * HID;
#pragma unroll
  for (int r = 0; r < 4; r++){
    float d0 = dis[m0 + q * 4 + r];
    float d1 = dis[m0 + 16 + q * 4 + r];
    crow0[(size_t)r * HID]      = f2bf(acc00[r] * d0);
    crow0[(size_t)r * HID + 64] = f2bf(acc01[r] * d0);
    crow1[(size_t)r * HID]      = f2bf(acc10[r] * d1);
    crow1[(size_t)r * HID + 64] = f2bf(acc11[r] * d1);
  }
}

// ------- aggregation: wave/node, readlane broadcast, ILP 16/8/4 ----------
// h_i = relu( dis_i * (sum_e w_e * g[src_e] + g_i) + b )   [R11 form]
__global__ __launch_bounds__(256) void k_aggregate(
    const int* __restrict__ row_start, const int* __restrict__ counts,
    const u32* __restrict__ csr, const float* __restrict__ dis,
    const u16* __restrict__ g, const float* __restrict__ bias,
    u16* __restrict__ hout){
  int node = blockIdx.x * 4 + (threadIdx.x >> 6);
  int lane = threadIdx.x & 63;
  int s = row_start[node], c = counts[node];
  const u32* gp = (const u32*)g;
  u32 sv = gp[((size_t)node << 6) + lane];       // self-loop term g_i
  f32x2 acc = {bf_lo(sv), bf_hi(sv)};
  for (int base = 0; base < c; base += 64){
    int nch = min(64, c - base);
    u32 sidx = 0; float ws = 0.f;
    if (lane < nch){
      u32 pw = csr[s + base + lane];             // coalesced 4B preload
      sidx = pw & 0x1FFFFu;                      // unpack ONCE per 64 edges
      ws = (float)(pw >> 17) * (1.f / 32767.f);
    }
    u32 wsb = __float_as_uint(ws);
    int j = 0;
#define GATH(T) \
    for (; j + T <= nch; j += T){ \
      u32 pv[T]; float wv[T]; \
      _Pragma("unroll") \
      for (int t = 0; t < T; t++){ \
        u32 st = (u32)__builtin_amdgcn_readlane(sidx, j + t); \
        wv[t] = __uint_as_float(__builtin_amdgcn_readlane(wsb, j + t)); \
        const u32* rowp = gp + st * 64u;         /* uniform base -> saddr form */ \
        pv[t] = rowp[lane]; \
      } \
      _Pragma("unroll") \
      for (int t = 0; t < T; t++){ \
        f32x2 val = {bf_lo(pv[t]), bf_hi(pv[t])}; \
        acc += wv[t] * val; \
      } \
    }
    GATH(16)
    GATH(8)
    GATH(4)
#undef GATH
    for (; j < nch; ++j){
      u32 st = (u32)__builtin_amdgcn_readlane(sidx, j);
      float wt = __uint_as_float(__builtin_amdgcn_readlane(wsb, j));
      const u32* rowp = gp + st * 64u;
      u32 pv = rowp[lane];
      f32x2 val = {bf_lo(pv), bf_hi(pv)};
      acc += wt * val;
    }
  }
  float di = dis[node];
  float2 bv = ((const float2*)bias)[lane];
  float o0 = fmaxf(acc.x * di + bv.x, 0.f);
  float o1 = fmaxf(acc.y * di + bv.y, 0.f);
  ((u32*)hout)[((size_t)node << 6) + lane] = (u32)f2bf(o0) | ((u32)f2bf(o1) << 16);
}

// -- readout: out[M,64] = [h1|h2] @ Wr^T + br (f32 out), 32 rows/block ----
__global__ __launch_bounds__(256) void k_readout(
    const u16* __restrict__ h1, const u16* __restrict__ h2,
    const u16* __restrict__ Wrb, const float* __restrict__ br, float* __restrict__ out){
  int wave = threadIdx.x >> 6, lane = threadIdx.x & 63;
  int m0 = blockIdx.x * 32;
  int n0 = wave * 16;
  int m = lane & 15, q = lane >> 4;
  const u16* a10 = h1 + (size_t)(m0 + m) * HID;
  const u16* a11 = a10 + (size_t)16 * HID;
  const u16* a20 = h2 + (size_t)(m0 + m) * HID;
  const u16* a21 = a20 + (size_t)16 * HID;
  const u16* b  = Wrb + (size_t)(n0 + m) * (2 * HID);
  f32x4 acc0 = {0.f,0.f,0.f,0.f}, acc1 = {0.f,0.f,0.f,0.f};
#pragma unroll
  for (int kb = 0; kb < HID; kb += 32){
    bf16x8 bf = ld8bf(b + kb + q * 8);
    acc0 = __builtin_amdgcn_mfma_f32_16x16x32_bf16(ld8bf(a10 + kb + q * 8), bf, acc0, 0, 0, 0);
    acc1 = __builtin_amdgcn_mfma_f32_16x16x32_bf16(ld8bf(a11 + kb + q * 8), bf, acc1, 0, 0, 0);
  }
#pragma unroll
  for (int kb = 0; kb < HID; kb += 32){
    bf16x8 bf = ld8bf(b + HID + kb + q * 8);
    acc0 = __builtin_amdgcn_mfma_f32_16x16x32_bf16(ld8bf(a20 + kb + q * 8), bf, acc0, 0, 0, 0);
    acc1 = __builtin_amdgcn_mfma_f32_16x16x32_bf16(ld8bf(a21 + kb + q * 8), bf, acc1, 0, 0, 0);
  }
  float bias = br[n0 + m];
  float* crow0 = out + (size_t)(m0 + q * 4) * ODIM + n0 + m;
  float* crow1 = crow0 + (size_t)16 * ODIM;
#pragma unroll
  for (int r = 0; r < 4; r++){
    crow0[(size_t)r * ODIM] = acc0[r] + bias;
    crow1[(size_t)r * ODIM] = acc1[r] + bias;
  }
}

// ---------------- launch --------------------------------------------------
extern "C" void kernel_launch(void* const* d_in, const int* in_sizes, int n_in,
                              void* d_out, int out_size, void* d_ws, size_t ws_size,
                              hipStream_t stream){
  const float* x     = (const float*)d_in[0];
  const int*   eidx  = (const int*)d_in[1];
  const float* eattr = (const float*)d_in[2];
  const float* W1    = (const float*)d_in[3];
  const float* b1    = (const float*)d_in[4];
  const float* W2    = (const float*)d_in[5];
  const float* b2    = (const float*)d_in[6];
  const float* Wr    = (const float*)d_in[7];
  const float* br    = (const float*)d_in[8];
  const int* erow  = eidx;        // edge_index[0]
  const int* ecol  = eidx + NE;   // edge_index[1]

  char* w = (char*)d_ws;
  auto carve = [&](size_t bytes) -> void* {
    void* p = (void*)w;
    w += (bytes + 255) & ~(size_t)255;
    return p;
  };
  u32* csr       = (u32*)carve((size_t)NBK * BINCAP * 4);    // bucket-padded, 4B recs
  u32* bcur      = (u32*)carve(256 * 4);      // contiguous with minmax (one memset)
  u32* minmax    = (u32*)carve(256);
  int* row_start = (int*)carve((size_t)NN * 4);
  int* counts    = (int*)carve((size_t)NN * 4);
  float* dis     = (float*)carve((size_t)NN * 4);
  u16* W1b       = (u16*)carve((size_t)HID * HID * 2);
  u16* W2b       = (u16*)carve((size_t)HID * HID * 2);
  u16* Wrb       = (u16*)carve((size_t)ODIM * 2 * HID * 2);
  u16* g         = (u16*)carve((size_t)NN * HID * 2);
  u16* h1        = (u16*)carve((size_t)NN * HID * 2);
  u16* h2        = (u16*)carve((size_t)NN * HID * 2);
  uint2* bin     = (uint2*)h2;   // alias: bin dead after k_sort, h2 written in layer 2

  hipMemsetAsync(bcur, 0, 1024 + 256, stream);   // bcur + minmax (graph-capturable)
  k_bin<<<BGRID + CVTB, 256, 0, stream>>>(eattr, erow, ecol, bcur, bin, minmax,
                                          W1, W2, Wr, W1b, W2b, Wrb);
  k_sort<<<NBK, 1024, 0, stream>>>(bcur, bin, minmax, csr, row_start, counts, dis);

  // layer 1: g = dis * (x @ W1^T)  (f32 A converted inline)
  k_gemm128<true><<<NN / 32, 256, 0, stream>>>(x, W1b, dis, g);
  k_aggregate<<<NN / 4, 256, 0, stream>>>(row_start, counts, csr, dis, g, b1, h1);
  // layer 2
  k_gemm128<false><<<NN / 32, 256, 0, stream>>>(h1, W2b, dis, g);
  k_aggregate<<<NN / 4, 256, 0, stream>>>(row_start, counts, csr, dis, g, b2, h2);
  // readout
  k_readout<<<NN / 32, 256, 0, stream>>>(h1, h2, Wrb, br, (float*)d_out);
}